// Round 3
// baseline (357.764 us; speedup 1.0000x reference)
//
#include <hip/hip_runtime.h>
#include <hip/hip_fp8.h>

#define DIM 128
#define LN_EPS 1e-5f
#define ECAP 640   // per-block staged edge capacity (32 nodes, mean deg 12.8 -> ~410; guarded fallback)

typedef __attribute__((ext_vector_type(8))) short s16x8;   // 8 bf16 in 4 VGPRs
typedef __attribute__((ext_vector_type(4))) float f32x4;
typedef __attribute__((ext_vector_type(2))) float f32x2;
typedef __attribute__((ext_vector_type(4))) unsigned int u32x4;
typedef __attribute__((ext_vector_type(2))) unsigned int u32x2;

__device__ __forceinline__ unsigned short f2bf(float f) {
    unsigned u = __float_as_uint(f);
    unsigned r = u + 0x7fffu + ((u >> 16) & 1u);   // round-to-nearest-even
    return (unsigned short)(r >> 16);
}
__device__ __forceinline__ float bf2f(unsigned short b) {
    return __uint_as_float(((unsigned)b) << 16);
}
__device__ __forceinline__ unsigned char f2fp8(float f) {
    return (unsigned char)__hip_cvt_float_to_fp8(f, __HIP_SATFINITE, __HIP_E4M3);
}
// accumulate 4 fp8 bytes (linear col order) into a[0..3]
__device__ __forceinline__ void acc_fp8x4(float* a, unsigned v) {
    f32x2 lo = __builtin_amdgcn_cvt_pk_f32_fp8(v, false);  // bytes 0,1
    f32x2 hi = __builtin_amdgcn_cvt_pk_f32_fp8(v, true);   // bytes 2,3
    a[0] += lo[0]; a[1] += lo[1]; a[2] += hi[0]; a[3] += hi[1];
}
// accumulate a full u32x4 (16 fp8 bytes) into a[0..15]
__device__ __forceinline__ void acc_fp8x16(float* a, u32x4 v) {
    acc_fp8x4(a + 0,  v[0]);
    acc_fp8x4(a + 4,  v[1]);
    acc_fp8x4(a + 8,  v[2]);
    acc_fp8x4(a + 12, v[3]);
}

// ---------------- CSR build ----------------

__global__ void count_deg(const int* __restrict__ dst, int E, int* __restrict__ counts) {
    int i = (blockIdx.x * 256 + threadIdx.x) * 4;
    if (i + 3 < E) {
        int4 d = *(const int4*)(dst + i);
        atomicAdd(&counts[d.x], 1);
        atomicAdd(&counts[d.y], 1);
        atomicAdd(&counts[d.z], 1);
        atomicAdd(&counts[d.w], 1);
    } else {
        for (int j = i; j < E; ++j) atomicAdd(&counts[dst[j]], 1);
    }
}

// --- multi-block scan, step 1: per-block partial sums (1024 elems / block of 256) ---
__global__ __launch_bounds__(256) void scan_partials(const int* __restrict__ counts, int n,
                                                     int* __restrict__ bsum) {
    int base = blockIdx.x * 1024 + threadIdx.x * 4;
    int s = 0;
#pragma unroll
    for (int j = 0; j < 4; ++j) {
        int i = base + j;
        if (i < n) s += counts[i];
    }
#pragma unroll
    for (int off = 32; off > 0; off >>= 1) s += __shfl_xor(s, off, 64);
    __shared__ int wsum[4];
    int lane = threadIdx.x & 63, wid = threadIdx.x >> 6;
    if (lane == 0) wsum[wid] = s;
    __syncthreads();
    if (threadIdx.x == 0) bsum[blockIdx.x] = wsum[0] + wsum[1] + wsum[2] + wsum[3];
}

// --- step 2: one wave scans the block sums ---
__global__ __launch_bounds__(64) void scan_bsums(const int* __restrict__ bsum,
                                                 int* __restrict__ bofs, int nb,
                                                 int* __restrict__ rowptr, int N, int E) {
    int lane = threadIdx.x;
    int carry = 0;
    for (int base = 0; base < nb; base += 64) {
        int v = (base + lane < nb) ? bsum[base + lane] : 0;
        int incl = v;
#pragma unroll
        for (int off = 1; off < 64; off <<= 1) {
            int t = __shfl_up(incl, off, 64);
            if (lane >= off) incl += t;
        }
        if (base + lane < nb) bofs[base + lane] = carry + incl - v;
        carry += __shfl(incl, 63, 64);
    }
    if (lane == 0) rowptr[N] = E;
}

// --- step 3: per-block scan with block offset; emit rowptr/cursor/dinv ---
__global__ __launch_bounds__(256) void scan_final(const int* __restrict__ counts, int n,
                                                  const int* __restrict__ bofs,
                                                  int* __restrict__ rowptr,
                                                  int* __restrict__ cursor,
                                                  float* __restrict__ dinv) {
    int base = blockIdx.x * 1024 + threadIdx.x * 4;
    int v[4];
#pragma unroll
    for (int j = 0; j < 4; ++j) {
        int i = base + j;
        v[j] = (i < n) ? counts[i] : 0;
    }
    int tsum = v[0] + v[1] + v[2] + v[3];
    int lane = threadIdx.x & 63, wid = threadIdx.x >> 6;
    int incl = tsum;
#pragma unroll
    for (int off = 1; off < 64; off <<= 1) {
        int t = __shfl_up(incl, off, 64);
        if (lane >= off) incl += t;
    }
    __shared__ int wsum[4];
    if (lane == 63) wsum[wid] = incl;
    __syncthreads();
    int wofs = 0;
    for (int w = 0; w < 4; ++w)
        if (w < wid) wofs += wsum[w];
    int excl = bofs[blockIdx.x] + wofs + (incl - tsum);
#pragma unroll
    for (int j = 0; j < 4; ++j) {
        int i = base + j;
        if (i < n) {
            rowptr[i] = excl;
            cursor[i] = excl;
            dinv[i] = 1.0f / (float)((v[j] > 1) ? v[j] : 1);
            excl += v[j];
        }
    }
}

__global__ void fill_csr(const int* __restrict__ src, const int* __restrict__ dst, int E,
                         int* __restrict__ cursor, int* __restrict__ srcidx) {
    int i = (blockIdx.x * 256 + threadIdx.x) * 4;
    if (i + 3 < E) {
        int4 s = *(const int4*)(src + i);
        int4 d = *(const int4*)(dst + i);
        int p0 = atomicAdd(&cursor[d.x], 1); srcidx[p0] = s.x;
        int p1 = atomicAdd(&cursor[d.y], 1); srcidx[p1] = s.y;
        int p2 = atomicAdd(&cursor[d.z], 1); srcidx[p2] = s.z;
        int p3 = atomicAdd(&cursor[d.w], 1); srcidx[p3] = s.w;
    } else {
        for (int j = i; j < E; ++j) {
            int p = atomicAdd(&cursor[dst[j]], 1);
            srcidx[p] = src[j];
        }
    }
}

// ---------------- weight conversion: f32 row-major -> bf16 transposed ----------------

__global__ __launch_bounds__(256) void cvt_weights(const float* __restrict__ in_w,
                                                   const float* __restrict__ w1,
                                                   const float* __restrict__ w2,
                                                   unsigned short* __restrict__ wt, int L) {
    int mat = blockIdx.x >> 3, part = blockIdx.x & 7;
    const float* src;
    if (mat == 0) src = in_w;
    else if (mat <= L) src = w1 + (size_t)(mat - 1) * DIM * DIM;
    else src = w2 + (size_t)(mat - 1 - L) * DIM * DIM;
    unsigned short* dst = wt + (size_t)mat * DIM * DIM;
    int base = part * 2048 + threadIdx.x;
#pragma unroll
    for (int j = 0; j < 8; ++j) {
        int i = base + j * 256;
        int k = i >> 7, n = i & 127;
        dst[n * DIM + k] = f2bf(src[i]);
    }
}

// ---------------- input projection (MFMA, col-split): hb/h8 = x @ in_w + in_b ----
// block = 16 rows, 4 waves; wave s computes cols [s*32, s*32+32). No LDS, no barrier.

__global__ __launch_bounds__(256) void gemm_bias_mfma(const float* __restrict__ x,
                                                      const unsigned short* __restrict__ Wt,
                                                      const float* __restrict__ bias,
                                                      unsigned short* __restrict__ hb,
                                                      unsigned char* __restrict__ h8, int N) {
    int tid = threadIdx.x;
    int s = tid >> 6, lane = tid & 63;
    int quad = lane >> 4, l16 = lane & 15;
    int r0 = blockIdx.x * 16;
    int cs = s * 32;
    int arow = r0 + l16;
    bool av = arow < N;

    f32x4 acc[2];
    acc[0] = (f32x4){0.f, 0.f, 0.f, 0.f};
    acc[1] = (f32x4){0.f, 0.f, 0.f, 0.f};

    const float4* xp = (const float4*)(x + ((size_t)(av ? arow : 0) << 7)) + quad * 2;
#pragma unroll
    for (int k0 = 0; k0 < 128; k0 += 32) {
        s16x8 a = {0, 0, 0, 0, 0, 0, 0, 0};
        if (av) {
            float4 f0 = xp[k0 / 4];
            float4 f1 = xp[k0 / 4 + 1];
            a[0] = (short)f2bf(f0.x); a[1] = (short)f2bf(f0.y);
            a[2] = (short)f2bf(f0.z); a[3] = (short)f2bf(f0.w);
            a[4] = (short)f2bf(f1.x); a[5] = (short)f2bf(f1.y);
            a[6] = (short)f2bf(f1.z); a[7] = (short)f2bf(f1.w);
        }
        s16x8 b0 = *(const s16x8*)(Wt + ((size_t)(cs + l16) << 7) + quad * 8 + k0);
        s16x8 b1 = *(const s16x8*)(Wt + ((size_t)(cs + 16 + l16) << 7) + quad * 8 + k0);
        acc[0] = __builtin_amdgcn_mfma_f32_16x16x32_bf16(a, b0, acc[0], 0, 0, 0);
        acc[1] = __builtin_amdgcn_mfma_f32_16x16x32_bf16(a, b1, acc[1], 0, 0, 0);
    }

#pragma unroll
    for (int c = 0; c < 2; ++c) {
        int col = cs + c * 16 + l16;
        float bv = bias[col];
#pragma unroll
        for (int reg = 0; reg < 4; ++reg) {
            int grow = r0 + quad * 4 + reg;
            if (grow < N) {
                float o = acc[c][reg] + bv;
                hb[((size_t)grow << 7) + col] = f2bf(o);
                h8[((size_t)grow << 7) + col] = f2fp8(o);
            }
        }
    }
}

// ---------------- fused layer v3: full-row gather, 32-node blocks ----------------
// block = 256 threads = 4 waves; block handles 32 nodes. Wave w owns nodes
// [r0+w*8, r0+w*8+8) with ALL 128 cols: 8 lanes/node, 16 B (16 fp8 cols) per lane.
// Each gather instruction = 8 edges x full 128-B row, perfectly coalesced ->
// 1 L2 request per edge (was 4x 32-B requests). No cross-lane reduce needed
// (lanes own disjoint cols). GEMMs: 32-row tile, B-fragments reused across the
// two 16-row subtiles.

__global__ __launch_bounds__(256) void agg_mlp_ln(const unsigned short* __restrict__ hin,
                                                  const unsigned char* __restrict__ h8in,
                                                  const int* __restrict__ rowptr,
                                                  const int* __restrict__ srcidx,
                                                  const float* __restrict__ dinv,
                                                  const unsigned short* __restrict__ W1t,
                                                  const float* __restrict__ B1,
                                                  const unsigned short* __restrict__ W2t,
                                                  const float* __restrict__ B2,
                                                  const float* __restrict__ G,
                                                  const float* __restrict__ Bb,
                                                  unsigned short* __restrict__ hout,
                                                  unsigned char* __restrict__ h8out,
                                                  float* __restrict__ out_f32, int N) {
    __shared__ unsigned short M[32][132];   // +4 pad: conflict-light b128 A-frag reads
    __shared__ unsigned short P[32][132];
    __shared__ float s1p[4][32], s2p[4][32];
    __shared__ int eL[ECAP];
    __shared__ int rp[33];

    int tid = threadIdx.x;
    int w = tid >> 6, lane = tid & 63;
    int quad = lane >> 4, l16 = lane & 15;
    int g = lane >> 3, li = lane & 7;       // gather: 8 groups/wave, 8 lanes/group
    int r0 = blockIdx.x * 32;
    int cs = w * 32;

    // ---- stage rowptr + edge list for the block (contiguous CSR range) ----
    if (tid < 33) {
        int idx = r0 + tid;
        rp[tid] = rowptr[idx < N ? idx : N];
    }
    __syncthreads();
    int ebase = rp[0];
    int etot = rp[32] - ebase;
    int estg = etot < ECAP ? etot : ECAP;
    for (int i = tid; i < estg; i += 256) eL[i] = srcidx[ebase + i];
    __syncthreads();

    // ---- gather: full-row, 8 lanes/node, batch 4, 2-deep pipeline ----
    int nrow = w * 8 + g;                  // node row within block
    int nd = r0 + nrow;
    bool nv = nd < N;
    int ls = rp[nrow] - ebase;
    int le = rp[nrow + 1] - ebase;
    if (!nv) { ls = 0; le = 0; }
    float di = nv ? dinv[nd] : 0.f;        // hoisted; covered by gather

    const unsigned char* hsl = h8in + li * 16;   // lane's 16-B slice of a row

    float a[16];
#pragma unroll
    for (int j = 0; j < 16; ++j) a[j] = 0.f;

    // idx fetch: broadcast ds_read (8 lanes of group read same address); guarded
    // fallback to global srcidx only if the block's edge range overflowed ECAP.
#define LIDX(jj) (((jj) < le) ? (((jj) < ECAP) ? eL[(jj)] : srcidx[ebase + (jj)]) : -1)

    int jA = ls;
    int iA0 = LIDX(jA + 0), iA1 = LIDX(jA + 1), iA2 = LIDX(jA + 2), iA3 = LIDX(jA + 3);
    u32x4 A0 = {0, 0, 0, 0}, A1 = {0, 0, 0, 0}, A2 = {0, 0, 0, 0}, A3 = {0, 0, 0, 0};
    if (iA0 >= 0) A0 = *(const u32x4*)(hsl + ((size_t)iA0 << 7));
    if (iA1 >= 0) A1 = *(const u32x4*)(hsl + ((size_t)iA1 << 7));
    if (iA2 >= 0) A2 = *(const u32x4*)(hsl + ((size_t)iA2 << 7));
    if (iA3 >= 0) A3 = *(const u32x4*)(hsl + ((size_t)iA3 << 7));
    int jB = jA + 4;
    int iB0 = LIDX(jB + 0), iB1 = LIDX(jB + 1), iB2 = LIDX(jB + 2), iB3 = LIDX(jB + 3);

    while (__any(jA < le)) {
        // issue batch B gathers (indices already resident)
        u32x4 B0 = {0, 0, 0, 0}, B1v = {0, 0, 0, 0}, B2v = {0, 0, 0, 0}, B3 = {0, 0, 0, 0};
        if (iB0 >= 0) B0  = *(const u32x4*)(hsl + ((size_t)iB0 << 7));
        if (iB1 >= 0) B1v = *(const u32x4*)(hsl + ((size_t)iB1 << 7));
        if (iB2 >= 0) B2v = *(const u32x4*)(hsl + ((size_t)iB2 << 7));
        if (iB3 >= 0) B3  = *(const u32x4*)(hsl + ((size_t)iB3 << 7));
        // read batch C indices from LDS (overlaps batch-A accumulate)
        int jC = jB + 4;
        int iC0 = LIDX(jC + 0), iC1 = LIDX(jC + 1), iC2 = LIDX(jC + 2), iC3 = LIDX(jC + 3);
        // accumulate batch A (zeros if inactive — fp8 0x00 == 0.0f)
        acc_fp8x16(a, A0);
        acc_fp8x16(a, A1);
        acc_fp8x16(a, A2);
        acc_fp8x16(a, A3);
        // shift pipeline
        jA = jB; A0 = B0; A1 = B1v; A2 = B2v; A3 = B3;
        jB = jC; iB0 = iC0; iB1 = iC1; iB2 = iC2; iB3 = iC3;
    }
#undef LIDX

    // ---- write m-row slice: node nrow, cols [li*16, li*16+16) ----
    {
        u32x4 o0, o1;
#pragma unroll
        for (int j = 0; j < 4; ++j) {
            unsigned lo0 = f2bf(a[2 * j]     * di);
            unsigned hi0 = f2bf(a[2 * j + 1] * di);
            o0[j] = lo0 | (hi0 << 16);
            unsigned lo1 = f2bf(a[8 + 2 * j]     * di);
            unsigned hi1 = f2bf(a[8 + 2 * j + 1] * di);
            o1[j] = lo1 | (hi1 << 16);
        }
        *(u32x4*)(&M[nrow][li * 16])     = o0;
        *(u32x4*)(&M[nrow][li * 16 + 8]) = o1;
    }
    __syncthreads();

    // ---- prefetch residual (used after GEMM2; covered by both GEMMs) ----
    unsigned short hvr[2][2][4];
#pragma unroll
    for (int rt = 0; rt < 2; ++rt) {
#pragma unroll
        for (int c = 0; c < 2; ++c) {
            int col = cs + c * 16 + l16;
#pragma unroll
            for (int reg = 0; reg < 4; ++reg) {
                int grow = r0 + rt * 16 + quad * 4 + reg;
                hvr[rt][c][reg] = (grow < N) ? hin[((size_t)grow << 7) + col] : (unsigned short)0;
            }
        }
    }

    // ---- GEMM1: relu(m @ W1 + b1); wave: 32 rows x 32 cols, B-frags shared ----
    f32x4 ac1[2][2];
    ac1[0][0] = (f32x4){0.f, 0.f, 0.f, 0.f}; ac1[0][1] = (f32x4){0.f, 0.f, 0.f, 0.f};
    ac1[1][0] = (f32x4){0.f, 0.f, 0.f, 0.f}; ac1[1][1] = (f32x4){0.f, 0.f, 0.f, 0.f};
#pragma unroll
    for (int k0 = 0; k0 < 128; k0 += 32) {
        s16x8 b0 = *(const s16x8*)(W1t + ((size_t)(cs + l16) << 7) + quad * 8 + k0);
        s16x8 b1 = *(const s16x8*)(W1t + ((size_t)(cs + 16 + l16) << 7) + quad * 8 + k0);
        s16x8 a0 = *(const s16x8*)(&M[l16][quad * 8 + k0]);
        s16x8 a1 = *(const s16x8*)(&M[16 + l16][quad * 8 + k0]);
        ac1[0][0] = __builtin_amdgcn_mfma_f32_16x16x32_bf16(a0, b0, ac1[0][0], 0, 0, 0);
        ac1[0][1] = __builtin_amdgcn_mfma_f32_16x16x32_bf16(a0, b1, ac1[0][1], 0, 0, 0);
        ac1[1][0] = __builtin_amdgcn_mfma_f32_16x16x32_bf16(a1, b0, ac1[1][0], 0, 0, 0);
        ac1[1][1] = __builtin_amdgcn_mfma_f32_16x16x32_bf16(a1, b1, ac1[1][1], 0, 0, 0);
    }
#pragma unroll
    for (int rt = 0; rt < 2; ++rt) {
#pragma unroll
        for (int c = 0; c < 2; ++c) {
            int col = cs + c * 16 + l16;
            float bv = B1[col];
#pragma unroll
            for (int reg = 0; reg < 4; ++reg) {
                float v = fmaxf(ac1[rt][c][reg] + bv, 0.f);
                P[rt * 16 + quad * 4 + reg][col] = f2bf(v);
            }
        }
    }
    __syncthreads();

    // ---- GEMM2: P @ W2 ----
    f32x4 ac2[2][2];
    ac2[0][0] = (f32x4){0.f, 0.f, 0.f, 0.f}; ac2[0][1] = (f32x4){0.f, 0.f, 0.f, 0.f};
    ac2[1][0] = (f32x4){0.f, 0.f, 0.f, 0.f}; ac2[1][1] = (f32x4){0.f, 0.f, 0.f, 0.f};
#pragma unroll
    for (int k0 = 0; k0 < 128; k0 += 32) {
        s16x8 b0 = *(const s16x8*)(W2t + ((size_t)(cs + l16) << 7) + quad * 8 + k0);
        s16x8 b1 = *(const s16x8*)(W2t + ((size_t)(cs + 16 + l16) << 7) + quad * 8 + k0);
        s16x8 a0 = *(const s16x8*)(&P[l16][quad * 8 + k0]);
        s16x8 a1 = *(const s16x8*)(&P[16 + l16][quad * 8 + k0]);
        ac2[0][0] = __builtin_amdgcn_mfma_f32_16x16x32_bf16(a0, b0, ac2[0][0], 0, 0, 0);
        ac2[0][1] = __builtin_amdgcn_mfma_f32_16x16x32_bf16(a0, b1, ac2[0][1], 0, 0, 0);
        ac2[1][0] = __builtin_amdgcn_mfma_f32_16x16x32_bf16(a1, b0, ac2[1][0], 0, 0, 0);
        ac2[1][1] = __builtin_amdgcn_mfma_f32_16x16x32_bf16(a1, b1, ac2[1][1], 0, 0, 0);
    }

    // ---- epilogue: residual + LN (cross-wave row sums via LDS partials) ----
    float z[2][2][4];
    float ps1[2][4] = {{0, 0, 0, 0}, {0, 0, 0, 0}};
    float ps2[2][4] = {{0, 0, 0, 0}, {0, 0, 0, 0}};
#pragma unroll
    for (int rt = 0; rt < 2; ++rt) {
#pragma unroll
        for (int c = 0; c < 2; ++c) {
            int col = cs + c * 16 + l16;
            float b2v = B2[col];
#pragma unroll
            for (int reg = 0; reg < 4; ++reg) {
                float hv = bf2f(hvr[rt][c][reg]);
                float zz = ac2[rt][c][reg] + b2v + hv;
                z[rt][c][reg] = zz;
                ps1[rt][reg] += zz;
                ps2[rt][reg] += zz * zz;
            }
        }
    }
#pragma unroll
    for (int off = 1; off < 16; off <<= 1) {
#pragma unroll
        for (int rt = 0; rt < 2; ++rt) {
#pragma unroll
            for (int reg = 0; reg < 4; ++reg) {
                ps1[rt][reg] += __shfl_xor(ps1[rt][reg], off, 64);
                ps2[rt][reg] += __shfl_xor(ps2[rt][reg], off, 64);
            }
        }
    }
    if (l16 == 0) {
#pragma unroll
        for (int rt = 0; rt < 2; ++rt) {
#pragma unroll
            for (int reg = 0; reg < 4; ++reg) {
                s1p[w][rt * 16 + quad * 4 + reg] = ps1[rt][reg];
                s2p[w][rt * 16 + quad * 4 + reg] = ps2[rt][reg];
            }
        }
    }
    __syncthreads();

#pragma unroll
    for (int rt = 0; rt < 2; ++rt) {
#pragma unroll
        for (int reg = 0; reg < 4; ++reg) {
            int row = rt * 16 + quad * 4 + reg;
            float S1 = s1p[0][row] + s1p[1][row] + s1p[2][row] + s1p[3][row];
            float S2 = s2p[0][row] + s2p[1][row] + s2p[2][row] + s2p[3][row];
            float mean = S1 * (1.0f / 128.0f);
            float var = S2 * (1.0f / 128.0f) - mean * mean;
            float rs = rsqrtf(var + LN_EPS);
            int grow = r0 + row;
            if (grow < N) {
#pragma unroll
                for (int c = 0; c < 2; ++c) {
                    int col = cs + c * 16 + l16;
                    float o = (z[rt][c][reg] - mean) * rs * G[col] + Bb[col];
                    if (out_f32) {
                        out_f32[((size_t)grow << 7) + col] = o;   // last layer: f32 only
                    } else {
                        hout[((size_t)grow << 7) + col] = f2bf(o);
                        h8out[((size_t)grow << 7) + col] = f2fp8(o);
                    }
                }
            }
        }
    }
}

// ---------------- launch ----------------

extern "C" void kernel_launch(void* const* d_in, const int* in_sizes, int n_in,
                              void* d_out, int out_size, void* d_ws, size_t ws_size,
                              hipStream_t stream) {
    const float* x    = (const float*)d_in[0];
    const int*   ei   = (const int*)d_in[1];
    const float* in_w = (const float*)d_in[2];
    const float* in_b = (const float*)d_in[3];
    const float* w1   = (const float*)d_in[4];
    const float* b1   = (const float*)d_in[5];
    const float* w2   = (const float*)d_in[6];
    const float* b2   = (const float*)d_in[7];
    const float* ln_g = (const float*)d_in[8];
    const float* ln_b = (const float*)d_in[9];

    const int N = in_sizes[0] / DIM;               // 50000
    const int E = in_sizes[1] / 2;                 // 640000
    const int LAYERS = in_sizes[4] / (DIM * DIM);  // 3

    const int* e_src = ei;
    const int* e_dst = ei + E;

    // workspace layout
    char* ws = (char*)d_ws;
    unsigned short* hb0    = (unsigned short*)ws;  ws += (size_t)N * DIM * 2;
    unsigned short* hb1    = (unsigned short*)ws;  ws += (size_t)N * DIM * 2;
    unsigned char*  h8a    = (unsigned char*)ws;   ws += (size_t)N * DIM;
    unsigned char*  h8b    = (unsigned char*)ws;   ws += (size_t)N * DIM;
    int*            counts = (int*)ws;             ws += (size_t)N * 4;
    int*            rowptr = (int*)ws;             ws += (size_t)(N + 1) * 4;
    int*            cursor = (int*)ws;             ws += (size_t)N * 4;
    float*          dinv   = (float*)ws;           ws += (size_t)N * 4;
    int*            srcidx = (int*)ws;             ws += (size_t)E * 4;
    int*            bsum   = (int*)ws;             ws += 4096;
    int*            bofs   = (int*)ws;             ws += 4096;
    unsigned short* wt     = (unsigned short*)ws;  ws += (size_t)(2 * LAYERS + 1) * DIM * DIM * 2;

    const int nScanBlocks = (N + 1023) / 1024;
    const int nMat = 2 * LAYERS + 1;

    // --- CSR build (deg is layer-invariant) + weight conversion ---
    (void)hipMemsetAsync(counts, 0, (size_t)N * 4, stream);
    count_deg<<<(E + 1023) / 1024, 256, 0, stream>>>(e_dst, E, counts);
    scan_partials<<<nScanBlocks, 256, 0, stream>>>(counts, N, bsum);
    scan_bsums<<<1, 64, 0, stream>>>(bsum, bofs, nScanBlocks, rowptr, N, E);
    scan_final<<<nScanBlocks, 256, 0, stream>>>(counts, N, bofs, rowptr, cursor, dinv);
    fill_csr<<<(E + 1023) / 1024, 256, 0, stream>>>(e_src, e_dst, E, cursor, srcidx);
    cvt_weights<<<nMat * 8, 256, 0, stream>>>(in_w, w1, w2, wt, LAYERS);

    const unsigned short* in_wt = wt;
    const unsigned short* w1t   = wt + (size_t)DIM * DIM;
    const unsigned short* w2t   = wt + (size_t)(1 + LAYERS) * DIM * DIM;

    // --- input projection ---
    gemm_bias_mfma<<<(N + 15) / 16, 256, 0, stream>>>(x, in_wt, in_b, hb0, h8a, N);

    // --- layers (ping-pong; gather reads pre-update fp8 table) ---
    int agg_grid = (N + 31) / 32;
    unsigned short* hin  = hb0;  unsigned char* h8in  = h8a;
    unsigned short* hout = hb1;  unsigned char* h8out = h8b;
    for (int i = 0; i < LAYERS; ++i) {
        float* out = (i == LAYERS - 1) ? (float*)d_out : nullptr;
        agg_mlp_ln<<<agg_grid, 256, 0, stream>>>(hin, h8in, rowptr, srcidx, dinv,
                                                 w1t + (size_t)i * DIM * DIM, b1 + (size_t)i * DIM,
                                                 w2t + (size_t)i * DIM * DIM, b2 + (size_t)i * DIM,
                                                 ln_g + (size_t)i * DIM, ln_b + (size_t)i * DIM,
                                                 hout, h8out, out, N);
        unsigned short* t = hin; hin = hout; hout = t;
        unsigned char* t8 = h8in; h8in = h8out; h8out = t8;
    }
}

// Round 4
// 335.394 us; speedup vs baseline: 1.0667x; 1.0667x over previous
//
#include <hip/hip_runtime.h>
#include <hip/hip_fp8.h>

#define DIM 128
#define LN_EPS 1e-5f

typedef __attribute__((ext_vector_type(8))) short s16x8;   // 8 bf16 in 4 VGPRs
typedef __attribute__((ext_vector_type(4))) float f32x4;
typedef __attribute__((ext_vector_type(2))) float f32x2;
typedef __attribute__((ext_vector_type(4))) unsigned int u32x4;
typedef __attribute__((ext_vector_type(2))) unsigned int u32x2;

__device__ __forceinline__ unsigned short f2bf(float f) {
    unsigned u = __float_as_uint(f);
    unsigned r = u + 0x7fffu + ((u >> 16) & 1u);   // round-to-nearest-even
    return (unsigned short)(r >> 16);
}
__device__ __forceinline__ float bf2f(unsigned short b) {
    return __uint_as_float(((unsigned)b) << 16);
}
__device__ __forceinline__ unsigned char f2fp8(float f) {
    return (unsigned char)__hip_cvt_float_to_fp8(f, __HIP_SATFINITE, __HIP_E4M3);
}
// accumulate 4 fp8 bytes (linear col order) into a[0..3]
__device__ __forceinline__ void acc_fp8x4(float* a, unsigned v) {
    f32x2 lo = __builtin_amdgcn_cvt_pk_f32_fp8(v, false);  // bytes 0,1
    f32x2 hi = __builtin_amdgcn_cvt_pk_f32_fp8(v, true);   // bytes 2,3
    a[0] += lo[0]; a[1] += lo[1]; a[2] += hi[0]; a[3] += hi[1];
}
// accumulate a full u32x4 (16 fp8 bytes) into a[0..15]
__device__ __forceinline__ void acc_fp8x16(float* a, u32x4 v) {
    acc_fp8x4(a + 0,  v[0]);
    acc_fp8x4(a + 4,  v[1]);
    acc_fp8x4(a + 8,  v[2]);
    acc_fp8x4(a + 12, v[3]);
}

// ---------------- CSR build ----------------

__global__ void count_deg(const int* __restrict__ dst, int E, int* __restrict__ counts) {
    int i = (blockIdx.x * 256 + threadIdx.x) * 4;
    if (i + 3 < E) {
        int4 d = *(const int4*)(dst + i);
        atomicAdd(&counts[d.x], 1);
        atomicAdd(&counts[d.y], 1);
        atomicAdd(&counts[d.z], 1);
        atomicAdd(&counts[d.w], 1);
    } else {
        for (int j = i; j < E; ++j) atomicAdd(&counts[dst[j]], 1);
    }
}

// --- multi-block scan, step 1: per-block partial sums (1024 elems / block of 256) ---
__global__ __launch_bounds__(256) void scan_partials(const int* __restrict__ counts, int n,
                                                     int* __restrict__ bsum) {
    int base = blockIdx.x * 1024 + threadIdx.x * 4;
    int s = 0;
#pragma unroll
    for (int j = 0; j < 4; ++j) {
        int i = base + j;
        if (i < n) s += counts[i];
    }
#pragma unroll
    for (int off = 32; off > 0; off >>= 1) s += __shfl_xor(s, off, 64);
    __shared__ int wsum[4];
    int lane = threadIdx.x & 63, wid = threadIdx.x >> 6;
    if (lane == 0) wsum[wid] = s;
    __syncthreads();
    if (threadIdx.x == 0) bsum[blockIdx.x] = wsum[0] + wsum[1] + wsum[2] + wsum[3];
}

// --- step 2: one wave scans the block sums ---
__global__ __launch_bounds__(64) void scan_bsums(const int* __restrict__ bsum,
                                                 int* __restrict__ bofs, int nb,
                                                 int* __restrict__ rowptr, int N, int E) {
    int lane = threadIdx.x;
    int carry = 0;
    for (int base = 0; base < nb; base += 64) {
        int v = (base + lane < nb) ? bsum[base + lane] : 0;
        int incl = v;
#pragma unroll
        for (int off = 1; off < 64; off <<= 1) {
            int t = __shfl_up(incl, off, 64);
            if (lane >= off) incl += t;
        }
        if (base + lane < nb) bofs[base + lane] = carry + incl - v;
        carry += __shfl(incl, 63, 64);
    }
    if (lane == 0) rowptr[N] = E;
}

// --- step 3: per-block scan with block offset; emit rowptr/cursor/dinv ---
__global__ __launch_bounds__(256) void scan_final(const int* __restrict__ counts, int n,
                                                  const int* __restrict__ bofs,
                                                  int* __restrict__ rowptr,
                                                  int* __restrict__ cursor,
                                                  float* __restrict__ dinv) {
    int base = blockIdx.x * 1024 + threadIdx.x * 4;
    int v[4];
#pragma unroll
    for (int j = 0; j < 4; ++j) {
        int i = base + j;
        v[j] = (i < n) ? counts[i] : 0;
    }
    int tsum = v[0] + v[1] + v[2] + v[3];
    int lane = threadIdx.x & 63, wid = threadIdx.x >> 6;
    int incl = tsum;
#pragma unroll
    for (int off = 1; off < 64; off <<= 1) {
        int t = __shfl_up(incl, off, 64);
        if (lane >= off) incl += t;
    }
    __shared__ int wsum[4];
    if (lane == 63) wsum[wid] = incl;
    __syncthreads();
    int wofs = 0;
    for (int w = 0; w < 4; ++w)
        if (w < wid) wofs += wsum[w];
    int excl = bofs[blockIdx.x] + wofs + (incl - tsum);
#pragma unroll
    for (int j = 0; j < 4; ++j) {
        int i = base + j;
        if (i < n) {
            rowptr[i] = excl;
            cursor[i] = excl;
            dinv[i] = 1.0f / (float)((v[j] > 1) ? v[j] : 1);
            excl += v[j];
        }
    }
}

__global__ void fill_csr(const int* __restrict__ src, const int* __restrict__ dst, int E,
                         int* __restrict__ cursor, int* __restrict__ srcidx) {
    int i = (blockIdx.x * 256 + threadIdx.x) * 4;
    if (i + 3 < E) {
        int4 s = *(const int4*)(src + i);
        int4 d = *(const int4*)(dst + i);
        int p0 = atomicAdd(&cursor[d.x], 1); srcidx[p0] = s.x;
        int p1 = atomicAdd(&cursor[d.y], 1); srcidx[p1] = s.y;
        int p2 = atomicAdd(&cursor[d.z], 1); srcidx[p2] = s.z;
        int p3 = atomicAdd(&cursor[d.w], 1); srcidx[p3] = s.w;
    } else {
        for (int j = i; j < E; ++j) {
            int p = atomicAdd(&cursor[dst[j]], 1);
            srcidx[p] = src[j];
        }
    }
}

// ---------------- weight conversion: f32 row-major -> bf16 transposed ----------------

__global__ __launch_bounds__(256) void cvt_weights(const float* __restrict__ in_w,
                                                   const float* __restrict__ w1,
                                                   const float* __restrict__ w2,
                                                   unsigned short* __restrict__ wt, int L) {
    int mat = blockIdx.x >> 3, part = blockIdx.x & 7;
    const float* src;
    if (mat == 0) src = in_w;
    else if (mat <= L) src = w1 + (size_t)(mat - 1) * DIM * DIM;
    else src = w2 + (size_t)(mat - 1 - L) * DIM * DIM;
    unsigned short* dst = wt + (size_t)mat * DIM * DIM;
    int base = part * 2048 + threadIdx.x;
#pragma unroll
    for (int j = 0; j < 8; ++j) {
        int i = base + j * 256;
        int k = i >> 7, n = i & 127;
        dst[n * DIM + k] = f2bf(src[i]);
    }
}

// ---------------- input projection (MFMA, col-split): hb/h8 = x @ in_w + in_b ----
// block = 16 rows, 4 waves; wave s computes cols [s*32, s*32+32). No LDS, no barrier.

__global__ __launch_bounds__(256) void gemm_bias_mfma(const float* __restrict__ x,
                                                      const unsigned short* __restrict__ Wt,
                                                      const float* __restrict__ bias,
                                                      unsigned short* __restrict__ hb,
                                                      unsigned char* __restrict__ h8, int N) {
    int tid = threadIdx.x;
    int s = tid >> 6, lane = tid & 63;
    int quad = lane >> 4, l16 = lane & 15;
    int r0 = blockIdx.x * 16;
    int cs = s * 32;
    int arow = r0 + l16;
    bool av = arow < N;

    f32x4 acc[2];
    acc[0] = (f32x4){0.f, 0.f, 0.f, 0.f};
    acc[1] = (f32x4){0.f, 0.f, 0.f, 0.f};

    const float4* xp = (const float4*)(x + ((size_t)(av ? arow : 0) << 7)) + quad * 2;
#pragma unroll
    for (int k0 = 0; k0 < 128; k0 += 32) {
        s16x8 a = {0, 0, 0, 0, 0, 0, 0, 0};
        if (av) {
            float4 f0 = xp[k0 / 4];
            float4 f1 = xp[k0 / 4 + 1];
            a[0] = (short)f2bf(f0.x); a[1] = (short)f2bf(f0.y);
            a[2] = (short)f2bf(f0.z); a[3] = (short)f2bf(f0.w);
            a[4] = (short)f2bf(f1.x); a[5] = (short)f2bf(f1.y);
            a[6] = (short)f2bf(f1.z); a[7] = (short)f2bf(f1.w);
        }
        s16x8 b0 = *(const s16x8*)(Wt + ((size_t)(cs + l16) << 7) + quad * 8 + k0);
        s16x8 b1 = *(const s16x8*)(Wt + ((size_t)(cs + 16 + l16) << 7) + quad * 8 + k0);
        acc[0] = __builtin_amdgcn_mfma_f32_16x16x32_bf16(a, b0, acc[0], 0, 0, 0);
        acc[1] = __builtin_amdgcn_mfma_f32_16x16x32_bf16(a, b1, acc[1], 0, 0, 0);
    }

#pragma unroll
    for (int c = 0; c < 2; ++c) {
        int col = cs + c * 16 + l16;
        float bv = bias[col];
#pragma unroll
        for (int reg = 0; reg < 4; ++reg) {
            int grow = r0 + quad * 4 + reg;
            if (grow < N) {
                float o = acc[c][reg] + bv;
                hb[((size_t)grow << 7) + col] = f2bf(o);
                h8[((size_t)grow << 7) + col] = f2fp8(o);
            }
        }
    }
}

// ---------------- aggregation-only kernel ----------------
// block = 256 threads = 4 INDEPENDENT waves (no LDS, no barriers). Wave handles
// 8 nodes: 8 lanes/node, 16 B/lane = full 128-B fp8 row per edge, coalesced.
// 2-deep software pipeline, batch 4. Output m = (sum of neighbor rows) * dinv,
// bf16 [N][128]. High wave-level concurrency: gather latency hidden by waves,
// not barriers-coupled compute.

__global__ __launch_bounds__(256) void aggregate(const unsigned char* __restrict__ h8in,
                                                 const int* __restrict__ rowptr,
                                                 const int* __restrict__ srcidx,
                                                 const float* __restrict__ dinv,
                                                 unsigned short* __restrict__ mout, int N) {
    int tid = threadIdx.x;
    int w = tid >> 6, lane = tid & 63;
    int g = lane >> 3, li = lane & 7;
    int nd = blockIdx.x * 32 + w * 8 + g;
    bool nv = nd < N;

    int e  = nv ? rowptr[nd] : 0;
    int ee = nv ? rowptr[nd + 1] : 0;
    float di = nv ? dinv[nd] : 0.f;

    const unsigned char* hsl = h8in + li * 16;   // lane's 16-B slice of a row

    float a[16];
#pragma unroll
    for (int j = 0; j < 16; ++j) a[j] = 0.f;

#define GIDX(jj) (((jj) < ee) ? srcidx[(jj)] : -1)
    int jA = e;
    int iA0 = GIDX(jA + 0), iA1 = GIDX(jA + 1), iA2 = GIDX(jA + 2), iA3 = GIDX(jA + 3);
    u32x4 A0 = {0, 0, 0, 0}, A1 = {0, 0, 0, 0}, A2 = {0, 0, 0, 0}, A3 = {0, 0, 0, 0};
    if (iA0 >= 0) A0 = *(const u32x4*)(hsl + ((size_t)iA0 << 7));
    if (iA1 >= 0) A1 = *(const u32x4*)(hsl + ((size_t)iA1 << 7));
    if (iA2 >= 0) A2 = *(const u32x4*)(hsl + ((size_t)iA2 << 7));
    if (iA3 >= 0) A3 = *(const u32x4*)(hsl + ((size_t)iA3 << 7));
    int jB = jA + 4;
    int iB0 = GIDX(jB + 0), iB1 = GIDX(jB + 1), iB2 = GIDX(jB + 2), iB3 = GIDX(jB + 3);

    while (__any(jA < ee)) {
        // issue batch B gathers (indices already resident)
        u32x4 B0 = {0, 0, 0, 0}, B1v = {0, 0, 0, 0}, B2v = {0, 0, 0, 0}, B3 = {0, 0, 0, 0};
        if (iB0 >= 0) B0  = *(const u32x4*)(hsl + ((size_t)iB0 << 7));
        if (iB1 >= 0) B1v = *(const u32x4*)(hsl + ((size_t)iB1 << 7));
        if (iB2 >= 0) B2v = *(const u32x4*)(hsl + ((size_t)iB2 << 7));
        if (iB3 >= 0) B3  = *(const u32x4*)(hsl + ((size_t)iB3 << 7));
        // prefetch batch C indices (overlaps batch-A accumulate)
        int jC = jB + 4;
        int iC0 = GIDX(jC + 0), iC1 = GIDX(jC + 1), iC2 = GIDX(jC + 2), iC3 = GIDX(jC + 3);
        // accumulate batch A (zeros if inactive — fp8 0x00 == 0.0f)
        acc_fp8x16(a, A0);
        acc_fp8x16(a, A1);
        acc_fp8x16(a, A2);
        acc_fp8x16(a, A3);
        // shift pipeline
        jA = jB; A0 = B0; A1 = B1v; A2 = B2v; A3 = B3;
        jB = jC; iB0 = iC0; iB1 = iC1; iB2 = iC2; iB3 = iC3;
    }
#undef GIDX

    if (nv) {
        u32x4 o0, o1;
#pragma unroll
        for (int j = 0; j < 4; ++j) {
            unsigned lo0 = f2bf(a[2 * j]     * di);
            unsigned hi0 = f2bf(a[2 * j + 1] * di);
            o0[j] = lo0 | (hi0 << 16);
            unsigned lo1 = f2bf(a[8 + 2 * j]     * di);
            unsigned hi1 = f2bf(a[8 + 2 * j + 1] * di);
            o1[j] = lo1 | (hi1 << 16);
        }
        unsigned short* mp = mout + ((size_t)nd << 7) + li * 16;
        *(u32x4*)(mp)     = o0;
        *(u32x4*)(mp + 8) = o1;
    }
}

// ---------------- MLP + LN kernel (dense, streaming) ----------------
// block = 256 threads = 4 waves; 32 rows. Loads m tile coalesced (16 B/thread x2),
// then GEMM1 -> relu -> GEMM2 -> residual + LN, dual-format output.

__global__ __launch_bounds__(256) void mlp_ln(const unsigned short* __restrict__ hin,
                                              const unsigned short* __restrict__ m,
                                              const unsigned short* __restrict__ W1t,
                                              const float* __restrict__ B1,
                                              const unsigned short* __restrict__ W2t,
                                              const float* __restrict__ B2,
                                              const float* __restrict__ G,
                                              const float* __restrict__ Bb,
                                              unsigned short* __restrict__ hout,
                                              unsigned char* __restrict__ h8out,
                                              float* __restrict__ out_f32, int N) {
    __shared__ unsigned short M[32][132];   // +4 pad: conflict-light b128 A-frag reads
    __shared__ unsigned short P[32][132];
    __shared__ float s1p[4][32], s2p[4][32];

    int tid = threadIdx.x;
    int w = tid >> 6, lane = tid & 63;
    int quad = lane >> 4, l16 = lane & 15;
    int r0 = blockIdx.x * 32;
    int cs = w * 32;

    // ---- load m tile: 512 chunks of 16 B (8 bf16); thread does chunks tid, tid+256 ----
#pragma unroll
    for (int cc = 0; cc < 2; ++cc) {
        int c = tid + cc * 256;
        int row = c >> 4, colc = (c & 15) * 8;
        int grow = r0 + row;
        u32x4 v = {0, 0, 0, 0};
        if (grow < N) v = *(const u32x4*)(m + ((size_t)grow << 7) + colc);
        *(u32x4*)(&M[row][colc]) = v;
    }
    __syncthreads();

    // ---- prefetch residual (used after GEMM2; covered by both GEMMs) ----
    unsigned short hvr[2][2][4];
#pragma unroll
    for (int rt = 0; rt < 2; ++rt) {
#pragma unroll
        for (int c = 0; c < 2; ++c) {
            int col = cs + c * 16 + l16;
#pragma unroll
            for (int reg = 0; reg < 4; ++reg) {
                int grow = r0 + rt * 16 + quad * 4 + reg;
                hvr[rt][c][reg] = (grow < N) ? hin[((size_t)grow << 7) + col] : (unsigned short)0;
            }
        }
    }

    // ---- GEMM1: relu(m @ W1 + b1); wave: 32 rows x 32 cols, B-frags shared ----
    f32x4 ac1[2][2];
    ac1[0][0] = (f32x4){0.f, 0.f, 0.f, 0.f}; ac1[0][1] = (f32x4){0.f, 0.f, 0.f, 0.f};
    ac1[1][0] = (f32x4){0.f, 0.f, 0.f, 0.f}; ac1[1][1] = (f32x4){0.f, 0.f, 0.f, 0.f};
#pragma unroll
    for (int k0 = 0; k0 < 128; k0 += 32) {
        s16x8 b0 = *(const s16x8*)(W1t + ((size_t)(cs + l16) << 7) + quad * 8 + k0);
        s16x8 b1 = *(const s16x8*)(W1t + ((size_t)(cs + 16 + l16) << 7) + quad * 8 + k0);
        s16x8 a0 = *(const s16x8*)(&M[l16][quad * 8 + k0]);
        s16x8 a1 = *(const s16x8*)(&M[16 + l16][quad * 8 + k0]);
        ac1[0][0] = __builtin_amdgcn_mfma_f32_16x16x32_bf16(a0, b0, ac1[0][0], 0, 0, 0);
        ac1[0][1] = __builtin_amdgcn_mfma_f32_16x16x32_bf16(a0, b1, ac1[0][1], 0, 0, 0);
        ac1[1][0] = __builtin_amdgcn_mfma_f32_16x16x32_bf16(a1, b0, ac1[1][0], 0, 0, 0);
        ac1[1][1] = __builtin_amdgcn_mfma_f32_16x16x32_bf16(a1, b1, ac1[1][1], 0, 0, 0);
    }
#pragma unroll
    for (int rt = 0; rt < 2; ++rt) {
#pragma unroll
        for (int c = 0; c < 2; ++c) {
            int col = cs + c * 16 + l16;
            float bv = B1[col];
#pragma unroll
            for (int reg = 0; reg < 4; ++reg) {
                float v = fmaxf(ac1[rt][c][reg] + bv, 0.f);
                P[rt * 16 + quad * 4 + reg][col] = f2bf(v);
            }
        }
    }
    __syncthreads();

    // ---- GEMM2: P @ W2 ----
    f32x4 ac2[2][2];
    ac2[0][0] = (f32x4){0.f, 0.f, 0.f, 0.f}; ac2[0][1] = (f32x4){0.f, 0.f, 0.f, 0.f};
    ac2[1][0] = (f32x4){0.f, 0.f, 0.f, 0.f}; ac2[1][1] = (f32x4){0.f, 0.f, 0.f, 0.f};
#pragma unroll
    for (int k0 = 0; k0 < 128; k0 += 32) {
        s16x8 b0 = *(const s16x8*)(W2t + ((size_t)(cs + l16) << 7) + quad * 8 + k0);
        s16x8 b1 = *(const s16x8*)(W2t + ((size_t)(cs + 16 + l16) << 7) + quad * 8 + k0);
        s16x8 a0 = *(const s16x8*)(&P[l16][quad * 8 + k0]);
        s16x8 a1 = *(const s16x8*)(&P[16 + l16][quad * 8 + k0]);
        ac2[0][0] = __builtin_amdgcn_mfma_f32_16x16x32_bf16(a0, b0, ac2[0][0], 0, 0, 0);
        ac2[0][1] = __builtin_amdgcn_mfma_f32_16x16x32_bf16(a0, b1, ac2[0][1], 0, 0, 0);
        ac2[1][0] = __builtin_amdgcn_mfma_f32_16x16x32_bf16(a1, b0, ac2[1][0], 0, 0, 0);
        ac2[1][1] = __builtin_amdgcn_mfma_f32_16x16x32_bf16(a1, b1, ac2[1][1], 0, 0, 0);
    }

    // ---- epilogue: residual + LN (cross-wave row sums via LDS partials) ----
    float z[2][2][4];
    float ps1[2][4] = {{0, 0, 0, 0}, {0, 0, 0, 0}};
    float ps2[2][4] = {{0, 0, 0, 0}, {0, 0, 0, 0}};
#pragma unroll
    for (int rt = 0; rt < 2; ++rt) {
#pragma unroll
        for (int c = 0; c < 2; ++c) {
            int col = cs + c * 16 + l16;
            float b2v = B2[col];
#pragma unroll
            for (int reg = 0; reg < 4; ++reg) {
                float hv = bf2f(hvr[rt][c][reg]);
                float zz = ac2[rt][c][reg] + b2v + hv;
                z[rt][c][reg] = zz;
                ps1[rt][reg] += zz;
                ps2[rt][reg] += zz * zz;
            }
        }
    }
#pragma unroll
    for (int off = 1; off < 16; off <<= 1) {
#pragma unroll
        for (int rt = 0; rt < 2; ++rt) {
#pragma unroll
            for (int reg = 0; reg < 4; ++reg) {
                ps1[rt][reg] += __shfl_xor(ps1[rt][reg], off, 64);
                ps2[rt][reg] += __shfl_xor(ps2[rt][reg], off, 64);
            }
        }
    }
    if (l16 == 0) {
#pragma unroll
        for (int rt = 0; rt < 2; ++rt) {
#pragma unroll
            for (int reg = 0; reg < 4; ++reg) {
                s1p[w][rt * 16 + quad * 4 + reg] = ps1[rt][reg];
                s2p[w][rt * 16 + quad * 4 + reg] = ps2[rt][reg];
            }
        }
    }
    __syncthreads();

#pragma unroll
    for (int rt = 0; rt < 2; ++rt) {
#pragma unroll
        for (int reg = 0; reg < 4; ++reg) {
            int row = rt * 16 + quad * 4 + reg;
            float S1 = s1p[0][row] + s1p[1][row] + s1p[2][row] + s1p[3][row];
            float S2 = s2p[0][row] + s2p[1][row] + s2p[2][row] + s2p[3][row];
            float mean = S1 * (1.0f / 128.0f);
            float var = S2 * (1.0f / 128.0f) - mean * mean;
            float rs = rsqrtf(var + LN_EPS);
            int grow = r0 + row;
            if (grow < N) {
#pragma unroll
                for (int c = 0; c < 2; ++c) {
                    int col = cs + c * 16 + l16;
                    float o = (z[rt][c][reg] - mean) * rs * G[col] + Bb[col];
                    if (out_f32) {
                        out_f32[((size_t)grow << 7) + col] = o;   // last layer: f32 only
                    } else {
                        hout[((size_t)grow << 7) + col] = f2bf(o);
                        h8out[((size_t)grow << 7) + col] = f2fp8(o);
                    }
                }
            }
        }
    }
}

// ---------------- launch ----------------

extern "C" void kernel_launch(void* const* d_in, const int* in_sizes, int n_in,
                              void* d_out, int out_size, void* d_ws, size_t ws_size,
                              hipStream_t stream) {
    const float* x    = (const float*)d_in[0];
    const int*   ei   = (const int*)d_in[1];
    const float* in_w = (const float*)d_in[2];
    const float* in_b = (const float*)d_in[3];
    const float* w1   = (const float*)d_in[4];
    const float* b1   = (const float*)d_in[5];
    const float* w2   = (const float*)d_in[6];
    const float* b2   = (const float*)d_in[7];
    const float* ln_g = (const float*)d_in[8];
    const float* ln_b = (const float*)d_in[9];

    const int N = in_sizes[0] / DIM;               // 50000
    const int E = in_sizes[1] / 2;                 // 640000
    const int LAYERS = in_sizes[4] / (DIM * DIM);  // 3

    const int* e_src = ei;
    const int* e_dst = ei + E;

    // workspace layout
    char* ws = (char*)d_ws;
    unsigned short* hb0    = (unsigned short*)ws;  ws += (size_t)N * DIM * 2;
    unsigned short* hb1    = (unsigned short*)ws;  ws += (size_t)N * DIM * 2;
    unsigned char*  h8a    = (unsigned char*)ws;   ws += (size_t)N * DIM;
    unsigned char*  h8b    = (unsigned char*)ws;   ws += (size_t)N * DIM;
    int*            counts = (int*)ws;             ws += (size_t)N * 4;
    int*            rowptr = (int*)ws;             ws += (size_t)(N + 1) * 4;
    int*            cursor = (int*)ws;             ws += (size_t)N * 4;
    float*          dinv   = (float*)ws;           ws += (size_t)N * 4;
    int*            srcidx = (int*)ws;             ws += (size_t)E * 4;
    int*            bsum   = (int*)ws;             ws += 4096;
    int*            bofs   = (int*)ws;             ws += 4096;
    unsigned short* wt     = (unsigned short*)ws;  ws += (size_t)(2 * LAYERS + 1) * DIM * DIM * 2;
    unsigned short* mbuf   = (unsigned short*)ws;  ws += (size_t)N * DIM * 2;

    const int nScanBlocks = (N + 1023) / 1024;
    const int nMat = 2 * LAYERS + 1;

    // --- CSR build (deg is layer-invariant) + weight conversion ---
    (void)hipMemsetAsync(counts, 0, (size_t)N * 4, stream);
    count_deg<<<(E + 1023) / 1024, 256, 0, stream>>>(e_dst, E, counts);
    scan_partials<<<nScanBlocks, 256, 0, stream>>>(counts, N, bsum);
    scan_bsums<<<1, 64, 0, stream>>>(bsum, bofs, nScanBlocks, rowptr, N, E);
    scan_final<<<nScanBlocks, 256, 0, stream>>>(counts, N, bofs, rowptr, cursor, dinv);
    fill_csr<<<(E + 1023) / 1024, 256, 0, stream>>>(e_src, e_dst, E, cursor, srcidx);
    cvt_weights<<<nMat * 8, 256, 0, stream>>>(in_w, w1, w2, wt, LAYERS);

    const unsigned short* in_wt = wt;
    const unsigned short* w1t   = wt + (size_t)DIM * DIM;
    const unsigned short* w2t   = wt + (size_t)(1 + LAYERS) * DIM * DIM;

    // --- input projection ---
    gemm_bias_mfma<<<(N + 15) / 16, 256, 0, stream>>>(x, in_wt, in_b, hb0, h8a, N);

    // --- layers (ping-pong; gather reads pre-update fp8 table) ---
    int tile_grid = (N + 31) / 32;
    unsigned short* hin  = hb0;  unsigned char* h8in  = h8a;
    unsigned short* hout = hb1;  unsigned char* h8out = h8b;
    for (int i = 0; i < LAYERS; ++i) {
        float* out = (i == LAYERS - 1) ? (float*)d_out : nullptr;
        aggregate<<<tile_grid, 256, 0, stream>>>(h8in, rowptr, srcidx, dinv, mbuf, N);
        mlp_ln<<<tile_grid, 256, 0, stream>>>(hin, mbuf,
                                              w1t + (size_t)i * DIM * DIM, b1 + (size_t)i * DIM,
                                              w2t + (size_t)i * DIM * DIM, b2 + (size_t)i * DIM,
                                              ln_g + (size_t)i * DIM, ln_b + (size_t)i * DIM,
                                              hout, h8out, out, N);
        unsigned short* t = hin; hin = hout; hout = t;
        unsigned char* t8 = h8in; h8in = h8out; h8out = t8;
    }
}